// Round 1
// baseline (187.977 us; speedup 1.0000x reference)
//
#include <hip/hip_runtime.h>
#include <math.h>

namespace {
constexpr int kB = 256;
constexpr int kN = 1024;
constexpr int kC = 512;
constexpr int kNP1 = kN + 1;          // 1025 (visual rows + dustbin)
constexpr float kEPS = 1e-6f;
constexpr float kPOW = 0.9523809523809523f;  // ALPHA/(ALPHA+REG) = 1/1.05
constexpr int kNSplit = 4;
constexpr int kRowsPerSplit = kN / kNSplit;  // 256

// ws layout (in floats):
//   sim     : [0, kB*kNP1)                          262400 floats
//   gamma   : [kB*kNP1, +kB*kN)                     262144 floats
//   partial : [kB*kNP1 + kB*kN, +kNSplit*kB*kC)     524288 floats
constexpr size_t kSimOff = 0;
constexpr size_t kGammaOff = (size_t)kB * kNP1;
constexpr size_t kPartialOff = kGammaOff + (size_t)kB * kN;
}  // namespace

// ---------------------------------------------------------------------------
// K1: sim[b,n] = dot(p, v) / (max(|p|,1e-12) * max(|v|,1e-12))
// one wave (64 lanes) per row; 4 rows per 256-thread block
// ---------------------------------------------------------------------------
__global__ __launch_bounds__(256) void sim_kernel(
    const float* __restrict__ prompt,      // [B, C]
    const float* __restrict__ vis,         // [B, N, C]
    const float* __restrict__ dustbin,     // [C]
    float* __restrict__ sim) {             // [B, NP1]
  const int wid = threadIdx.x >> 6;
  const int lane = threadIdx.x & 63;
  const long long row = (long long)blockIdx.x * 4 + wid;
  if (row >= (long long)kB * kNP1) return;
  const int b = (int)(row / kNP1);
  const int n = (int)(row % kNP1);

  const float* vrow =
      (n < kN) ? (vis + ((size_t)b * kN + n) * kC) : dustbin;
  const float* prow = prompt + (size_t)b * kC;

  float dot = 0.f, vsq = 0.f, psq = 0.f;
#pragma unroll
  for (int h = 0; h < 2; ++h) {
    const int off = h * 256 + lane * 4;
    const float4 v4 = *reinterpret_cast<const float4*>(vrow + off);
    const float4 p4 = *reinterpret_cast<const float4*>(prow + off);
    dot += v4.x * p4.x + v4.y * p4.y + v4.z * p4.z + v4.w * p4.w;
    vsq += v4.x * v4.x + v4.y * v4.y + v4.z * v4.z + v4.w * v4.w;
    psq += p4.x * p4.x + p4.y * p4.y + p4.z * p4.z + p4.w * p4.w;
  }
#pragma unroll
  for (int s = 1; s < 64; s <<= 1) {
    dot += __shfl_xor(dot, s);
    vsq += __shfl_xor(vsq, s);
    psq += __shfl_xor(psq, s);
  }
  if (lane == 0) {
    const float pn = fmaxf(sqrtf(psq), 1e-12f);
    const float vn = fmaxf(sqrtf(vsq), 1e-12f);
    sim[row] = dot / (pn * vn);
  }
}

// ---------------------------------------------------------------------------
// K2: per-batch Sinkhorn (3 iters) entirely in one block.
// thread t owns n=t; thread 0 additionally owns the dustbin n=1024.
// writes gamma[b, 0..N) to ws and total_mass[b] to d_out tail.
// ---------------------------------------------------------------------------
__global__ __launch_bounds__(1024) void sinkhorn_kernel(
    const float* __restrict__ sim,     // [B, NP1]
    float* __restrict__ gamma,         // [B, N]
    float* __restrict__ mass_out) {    // [B]
  const int b = blockIdx.x;
  const int t = threadIdx.x;
  __shared__ float red[16];

  const float* simb = sim + (size_t)b * kNP1;
  const float K0 = expf((simb[t] - 1.0f) * 20.0f);
  const float K1 = (t == 0) ? expf((simb[kN] - 1.0f) * 20.0f) : 0.0f;
  float v0 = 1.0f, v1 = 1.0f;
  float u = 1.0f;

  for (int it = 0; it < 3; ++it) {
    float partial = K0 * v0 + K1 * v1;
#pragma unroll
    for (int s = 1; s < 64; s <<= 1) partial += __shfl_xor(partial, s);
    if ((t & 63) == 0) red[t >> 6] = partial;
    __syncthreads();
    float Kv = 0.f;
#pragma unroll
    for (int w = 0; w < 16; ++w) Kv += red[w];
    __syncthreads();

    u = powf(Kv + kEPS, -kPOW);          // (1/(Kv+eps))^POW
    v0 = powf(u * K0 + kEPS, -kPOW);
    v1 = powf(u * K1 + kEPS, -kPOW);
  }

  const float g0 = u * K0 * v0;          // n = t < N always
  gamma[(size_t)b * kN + t] = g0;

  // total_mass over n < N only (dustbin excluded)
  float partial = g0;
#pragma unroll
  for (int s = 1; s < 64; s <<= 1) partial += __shfl_xor(partial, s);
  if ((t & 63) == 0) red[t >> 6] = partial;
  __syncthreads();
  if (t == 0) {
    float m = 0.f;
#pragma unroll
    for (int w = 0; w < 16; ++w) m += red[w];
    mass_out[b] = m;
  }
}

// ---------------------------------------------------------------------------
// K3: partial p_obs. block (b,s) sums rows [s*256,(s+1)*256); thread = channel c.
// ---------------------------------------------------------------------------
__global__ __launch_bounds__(512) void pobs_kernel(
    const float* __restrict__ vis,       // [B, N, C]
    const float* __restrict__ gamma,     // [B, N]
    float* __restrict__ partial) {       // [B*NSplit, C]
  const int b = blockIdx.x / kNSplit;
  const int s = blockIdx.x % kNSplit;
  const int c = threadIdx.x;

  __shared__ float gs[kRowsPerSplit];
  const float* g = gamma + (size_t)b * kN + (size_t)s * kRowsPerSplit;
  for (int i = threadIdx.x; i < kRowsPerSplit; i += 512) gs[i] = g[i];
  __syncthreads();

  const float* vbase = vis + ((size_t)b * kN + (size_t)s * kRowsPerSplit) * kC;
  float acc = 0.f;
#pragma unroll 8
  for (int n = 0; n < kRowsPerSplit; ++n) {
    acc += gs[n] * vbase[(size_t)n * kC + c];
  }
  partial[(size_t)blockIdx.x * kC + c] = acc;
}

// ---------------------------------------------------------------------------
// K4: reduce the NSplit partials -> p_obs in d_out
// ---------------------------------------------------------------------------
__global__ __launch_bounds__(256) void reduce_kernel(
    const float* __restrict__ partial,   // [B*NSplit, C]
    float* __restrict__ p_obs) {         // [B, C]
  const int i = blockIdx.x * 256 + threadIdx.x;
  if (i >= kB * kC) return;
  const int b = i / kC;
  const int c = i % kC;
  float s = 0.f;
#pragma unroll
  for (int k = 0; k < kNSplit; ++k)
    s += partial[((size_t)(b * kNSplit + k)) * kC + c];
  p_obs[i] = s;
}

extern "C" void kernel_launch(void* const* d_in, const int* in_sizes, int n_in,
                              void* d_out, int out_size, void* d_ws,
                              size_t ws_size, hipStream_t stream) {
  const float* prompt = (const float*)d_in[0];    // [B,1,C]
  const float* vis = (const float*)d_in[1];       // [B,N,C]
  const float* dustbin = (const float*)d_in[2];   // [1,1,C]

  float* out = (float*)d_out;          // p_obs [B*C] then total_mass [B]
  float* ws = (float*)d_ws;

  float* sim = ws + kSimOff;
  float* gamma = ws + kGammaOff;
  float* partial = ws + kPartialOff;

  // K1: sim
  {
    const long long rows = (long long)kB * kNP1;
    const int blocks = (int)((rows + 3) / 4);
    sim_kernel<<<blocks, 256, 0, stream>>>(prompt, vis, dustbin, sim);
  }
  // K2: sinkhorn -> gamma, total_mass
  sinkhorn_kernel<<<kB, 1024, 0, stream>>>(sim, gamma, out + (size_t)kB * kC);
  // K3: partial p_obs
  pobs_kernel<<<kB * kNSplit, 512, 0, stream>>>(vis, gamma, partial);
  // K4: final reduce
  reduce_kernel<<<(kB * kC + 255) / 256, 256, 0, stream>>>(partial, out);
}

// Round 2
// 150.547 us; speedup vs baseline: 1.2486x; 1.2486x over previous
//
#include <hip/hip_runtime.h>
#include <math.h>

namespace {
constexpr int kB = 256;
constexpr int kN = 1024;
constexpr int kC = 512;
constexpr int kNP1 = kN + 1;  // 1025 (visual rows + dustbin)
constexpr float kEPS = 1e-6f;
constexpr float kPOW = 0.9523809523809523f;  // ALPHA/(ALPHA+REG) = 1/1.05
constexpr float kLOG2E = 1.44269504088896341f;

// ---- fast-path ws layout (bytes) ----
// vis8 : [0, kB*kN*kC)                     134,217,728 B (e4m3 copy of vis)
// sim  : [kVis8Bytes, +kB*kNP1*4)            1,049,600 B
constexpr size_t kVis8Bytes = (size_t)kB * kN * kC;
constexpr size_t kSimOffB = kVis8Bytes;
constexpr size_t kWsNeeded = kVis8Bytes + (size_t)kB * kNP1 * sizeof(float);

// ---- fallback ws layout (floats) ----
constexpr size_t kFbSimOff = 0;
constexpr size_t kFbGammaOff = (size_t)kB * kNP1;
constexpr size_t kFbPartialOff = kFbGammaOff + (size_t)kB * kN;
constexpr int kNSplit = 4;
constexpr int kRowsPerSplit = kN / kNSplit;  // 256

typedef float f32x2 __attribute__((ext_vector_type(2)));
}  // namespace

// ===========================================================================
// FAST PATH
// ===========================================================================

// K1: sim[b,n] for all 1025 rows; also write e4m3 copy of vis (n < N).
// One wave per row, lane owns 8 contiguous channels [lane*8, lane*8+8).
__global__ __launch_bounds__(256) void sim_fp8_kernel(
    const float* __restrict__ prompt,       // [B, C]
    const float* __restrict__ vis,          // [B, N, C]
    const float* __restrict__ dustbin,      // [C]
    float* __restrict__ sim,                // [B, NP1]
    unsigned char* __restrict__ vis8) {     // [B, N, C] e4m3
  const int wid = threadIdx.x >> 6;
  const int lane = threadIdx.x & 63;
  const long long row = (long long)blockIdx.x * 4 + wid;
  if (row >= (long long)kB * kNP1) return;
  const int b = (int)(row / kNP1);
  const int n = (int)(row % kNP1);

  const float* vrow = (n < kN) ? (vis + ((size_t)b * kN + n) * kC) : dustbin;
  const float* prow = prompt + (size_t)b * kC;
  const int off = lane * 8;

  const float4 va = *reinterpret_cast<const float4*>(vrow + off);
  const float4 vb = *reinterpret_cast<const float4*>(vrow + off + 4);
  const float4 pa = *reinterpret_cast<const float4*>(prow + off);
  const float4 pb = *reinterpret_cast<const float4*>(prow + off + 4);

  float dot = va.x * pa.x + va.y * pa.y + va.z * pa.z + va.w * pa.w +
              vb.x * pb.x + vb.y * pb.y + vb.z * pb.z + vb.w * pb.w;
  float vsq = va.x * va.x + va.y * va.y + va.z * va.z + va.w * va.w +
              vb.x * vb.x + vb.y * vb.y + vb.z * vb.z + vb.w * vb.w;
  float psq = pa.x * pa.x + pa.y * pa.y + pa.z * pa.z + pa.w * pa.w +
              pb.x * pb.x + pb.y * pb.y + pb.z * pb.z + pb.w * pb.w;

  // e4m3 copy (only real visual rows)
  if (n < kN) {
    int pk0 = __builtin_amdgcn_cvt_pk_fp8_f32(va.x, va.y, 0, false);
    pk0 = __builtin_amdgcn_cvt_pk_fp8_f32(va.z, va.w, pk0, true);
    int pk1 = __builtin_amdgcn_cvt_pk_fp8_f32(vb.x, vb.y, 0, false);
    pk1 = __builtin_amdgcn_cvt_pk_fp8_f32(vb.z, vb.w, pk1, true);
    uint2 w;
    w.x = (unsigned)pk0;
    w.y = (unsigned)pk1;
    *reinterpret_cast<uint2*>(vis8 + ((size_t)b * kN + n) * kC + off) = w;
  }

#pragma unroll
  for (int s = 1; s < 64; s <<= 1) {
    dot += __shfl_xor(dot, s);
    vsq += __shfl_xor(vsq, s);
    psq += __shfl_xor(psq, s);
  }
  if (lane == 0) {
    const float pn = fmaxf(sqrtf(psq), 1e-12f);
    const float vn = fmaxf(sqrtf(vsq), 1e-12f);
    sim[row] = dot / (pn * vn);
  }
}

// K2: per-batch Sinkhorn + einsum + both outputs, one 1024-thread block per b.
__global__ __launch_bounds__(1024) void sinkhorn_pobs_kernel(
    const float* __restrict__ sim,          // [B, NP1]
    const unsigned char* __restrict__ vis8, // [B, N, C] e4m3
    float* __restrict__ p_obs,              // [B, C]
    float* __restrict__ mass_out) {         // [B]
  const int b = blockIdx.x;
  const int t = threadIdx.x;
  __shared__ float red[16];
  __shared__ float gs[kN];
  __shared__ float lds[16][64][8];  // 32 KB

  const float* simb = sim + (size_t)b * kNP1;
  const float K0 = exp2f((simb[t] - 1.0f) * (20.0f * kLOG2E));
  const float Kd = (t == 0) ? exp2f((simb[kN] - 1.0f) * (20.0f * kLOG2E)) : 0.0f;
  float v0 = 1.0f, vd = 1.0f, u = 1.0f;

#pragma unroll
  for (int it = 0; it < 3; ++it) {
    float partial = K0 * v0 + Kd * vd;
#pragma unroll
    for (int s = 1; s < 64; s <<= 1) partial += __shfl_xor(partial, s);
    if ((t & 63) == 0) red[t >> 6] = partial;
    __syncthreads();
    float Kv = 0.f;
#pragma unroll
    for (int w = 0; w < 16; ++w) Kv += red[w];
    __syncthreads();
    // x^-POW = exp2(-POW * log2(x)); x > 0 always
    u = exp2f(-kPOW * log2f(Kv + kEPS));
    v0 = exp2f(-kPOW * log2f(u * K0 + kEPS));
    vd = exp2f(-kPOW * log2f(u * Kd + kEPS));
  }

  const float g = u * K0 * v0;  // gamma for n = t (< N always)
  gs[t] = g;

  // total_mass over n < N
  float pm = g;
#pragma unroll
  for (int s = 1; s < 64; s <<= 1) pm += __shfl_xor(pm, s);
  if ((t & 63) == 0) red[t >> 6] = pm;
  __syncthreads();  // also publishes gs[]
  if (t == 0) {
    float m = 0.f;
#pragma unroll
    for (int w = 0; w < 16; ++w) m += red[w];
    mass_out[b] = m;
  }

  // einsum: p_obs[c] = sum_n gs[n] * vis8[b,n,c]
  const int sub = t >> 6;       // 0..15  (== wave id -> gs[n] is a broadcast)
  const int cq = t & 63;        // channel group: channels [8*cq, 8*cq+8)
  float acc[8] = {0.f, 0.f, 0.f, 0.f, 0.f, 0.f, 0.f, 0.f};
  const unsigned char* vbase = vis8 + (size_t)b * kN * kC + (size_t)cq * 8;
#pragma unroll 4
  for (int k = 0; k < 64; ++k) {
    const int n = sub + (k << 4);
    const float gn = gs[n];
    const uint2 w = *reinterpret_cast<const uint2*>(vbase + (size_t)n * kC);
    const f32x2 f01 = __builtin_amdgcn_cvt_pk_f32_fp8(w.x, false);
    const f32x2 f23 = __builtin_amdgcn_cvt_pk_f32_fp8(w.x, true);
    const f32x2 f45 = __builtin_amdgcn_cvt_pk_f32_fp8(w.y, false);
    const f32x2 f67 = __builtin_amdgcn_cvt_pk_f32_fp8(w.y, true);
    acc[0] += gn * f01.x; acc[1] += gn * f01.y;
    acc[2] += gn * f23.x; acc[3] += gn * f23.y;
    acc[4] += gn * f45.x; acc[5] += gn * f45.y;
    acc[6] += gn * f67.x; acc[7] += gn * f67.y;
  }
#pragma unroll
  for (int j = 0; j < 8; ++j) lds[sub][cq][j] = acc[j];
  __syncthreads();
  if (t < 512) {
    // channel c == t: cq = t>>3, j = t&7
    float s = 0.f;
#pragma unroll
    for (int ss = 0; ss < 16; ++ss) s += lds[ss][t >> 3][t & 7];
    p_obs[(size_t)b * kC + t] = s;
  }
}

// ===========================================================================
// FALLBACK PATH (round-1 fp32 two-pass; used only if ws too small)
// ===========================================================================

__global__ __launch_bounds__(256) void sim_kernel(
    const float* __restrict__ prompt, const float* __restrict__ vis,
    const float* __restrict__ dustbin, float* __restrict__ sim) {
  const int wid = threadIdx.x >> 6;
  const int lane = threadIdx.x & 63;
  const long long row = (long long)blockIdx.x * 4 + wid;
  if (row >= (long long)kB * kNP1) return;
  const int b = (int)(row / kNP1);
  const int n = (int)(row % kNP1);
  const float* vrow = (n < kN) ? (vis + ((size_t)b * kN + n) * kC) : dustbin;
  const float* prow = prompt + (size_t)b * kC;
  float dot = 0.f, vsq = 0.f, psq = 0.f;
#pragma unroll
  for (int h = 0; h < 2; ++h) {
    const int off = h * 256 + lane * 4;
    const float4 v4 = *reinterpret_cast<const float4*>(vrow + off);
    const float4 p4 = *reinterpret_cast<const float4*>(prow + off);
    dot += v4.x * p4.x + v4.y * p4.y + v4.z * p4.z + v4.w * p4.w;
    vsq += v4.x * v4.x + v4.y * v4.y + v4.z * v4.z + v4.w * v4.w;
    psq += p4.x * p4.x + p4.y * p4.y + p4.z * p4.z + p4.w * p4.w;
  }
#pragma unroll
  for (int s = 1; s < 64; s <<= 1) {
    dot += __shfl_xor(dot, s);
    vsq += __shfl_xor(vsq, s);
    psq += __shfl_xor(psq, s);
  }
  if (lane == 0) {
    const float pn = fmaxf(sqrtf(psq), 1e-12f);
    const float vn = fmaxf(sqrtf(vsq), 1e-12f);
    sim[row] = dot / (pn * vn);
  }
}

__global__ __launch_bounds__(1024) void sinkhorn_kernel(
    const float* __restrict__ sim, float* __restrict__ gamma,
    float* __restrict__ mass_out) {
  const int b = blockIdx.x;
  const int t = threadIdx.x;
  __shared__ float red[16];
  const float* simb = sim + (size_t)b * kNP1;
  const float K0 = exp2f((simb[t] - 1.0f) * (20.0f * kLOG2E));
  const float K1 = (t == 0) ? exp2f((simb[kN] - 1.0f) * (20.0f * kLOG2E)) : 0.0f;
  float v0 = 1.0f, v1 = 1.0f, u = 1.0f;
  for (int it = 0; it < 3; ++it) {
    float partial = K0 * v0 + K1 * v1;
#pragma unroll
    for (int s = 1; s < 64; s <<= 1) partial += __shfl_xor(partial, s);
    if ((t & 63) == 0) red[t >> 6] = partial;
    __syncthreads();
    float Kv = 0.f;
#pragma unroll
    for (int w = 0; w < 16; ++w) Kv += red[w];
    __syncthreads();
    u = exp2f(-kPOW * log2f(Kv + kEPS));
    v0 = exp2f(-kPOW * log2f(u * K0 + kEPS));
    v1 = exp2f(-kPOW * log2f(u * K1 + kEPS));
  }
  const float g0 = u * K0 * v0;
  gamma[(size_t)b * kN + t] = g0;
  float partial = g0;
#pragma unroll
  for (int s = 1; s < 64; s <<= 1) partial += __shfl_xor(partial, s);
  if ((t & 63) == 0) red[t >> 6] = partial;
  __syncthreads();
  if (t == 0) {
    float m = 0.f;
#pragma unroll
    for (int w = 0; w < 16; ++w) m += red[w];
    mass_out[b] = m;
  }
}

__global__ __launch_bounds__(512) void pobs_kernel(
    const float* __restrict__ vis, const float* __restrict__ gamma,
    float* __restrict__ partial) {
  const int b = blockIdx.x / kNSplit;
  const int s = blockIdx.x % kNSplit;
  const int c = threadIdx.x;
  __shared__ float gsm[kRowsPerSplit];
  const float* g = gamma + (size_t)b * kN + (size_t)s * kRowsPerSplit;
  for (int i = threadIdx.x; i < kRowsPerSplit; i += 512) gsm[i] = g[i];
  __syncthreads();
  const float* vbase = vis + ((size_t)b * kN + (size_t)s * kRowsPerSplit) * kC;
  float acc = 0.f;
#pragma unroll 8
  for (int n = 0; n < kRowsPerSplit; ++n) acc += gsm[n] * vbase[(size_t)n * kC + c];
  partial[(size_t)blockIdx.x * kC + c] = acc;
}

__global__ __launch_bounds__(256) void reduce_kernel(
    const float* __restrict__ partial, float* __restrict__ p_obs) {
  const int i = blockIdx.x * 256 + threadIdx.x;
  if (i >= kB * kC) return;
  const int b = i / kC;
  const int c = i % kC;
  float s = 0.f;
#pragma unroll
  for (int k = 0; k < kNSplit; ++k)
    s += partial[((size_t)(b * kNSplit + k)) * kC + c];
  p_obs[i] = s;
}

// ===========================================================================

extern "C" void kernel_launch(void* const* d_in, const int* in_sizes, int n_in,
                              void* d_out, int out_size, void* d_ws,
                              size_t ws_size, hipStream_t stream) {
  const float* prompt = (const float*)d_in[0];
  const float* vis = (const float*)d_in[1];
  const float* dustbin = (const float*)d_in[2];
  float* out = (float*)d_out;  // p_obs [B*C] then total_mass [B]

  if (ws_size >= kWsNeeded) {
    unsigned char* vis8 = (unsigned char*)d_ws;
    float* sim = (float*)((unsigned char*)d_ws + kSimOffB);
    const long long rows = (long long)kB * kNP1;
    sim_fp8_kernel<<<(int)((rows + 3) / 4), 256, 0, stream>>>(
        prompt, vis, dustbin, sim, vis8);
    sinkhorn_pobs_kernel<<<kB, 1024, 0, stream>>>(
        sim, vis8, out, out + (size_t)kB * kC);
  } else {
    float* ws = (float*)d_ws;
    float* sim = ws + kFbSimOff;
    float* gamma = ws + kFbGammaOff;
    float* partial = ws + kFbPartialOff;
    const long long rows = (long long)kB * kNP1;
    sim_kernel<<<(int)((rows + 3) / 4), 256, 0, stream>>>(prompt, vis, dustbin, sim);
    sinkhorn_kernel<<<kB, 1024, 0, stream>>>(sim, gamma, out + (size_t)kB * kC);
    pobs_kernel<<<kB * kNSplit, 512, 0, stream>>>(vis, gamma, partial);
    reduce_kernel<<<(kB * kC + 255) / 256, 256, 0, stream>>>(partial, out);
  }
}